// Round 6
// baseline (199.538 us; speedup 1.0000x reference)
//
#include <hip/hip_runtime.h>
#include <math.h>

// Round 12: R11 skeleton (141us best), three local instruction cuts.
//   1. Encoder update pk-packed: ve[0..3] as 2x v2f; v_pk_add/mul_f32 are
//      IEEE per-half -> byte-identical to the scalar chain. cmp/sel/ballot
//      stay scalar. (exact)
//   2. Conv bias hoisted past the pool-max: rn(x+b) monotone in x, so
//      max_i(a_i)+b == max_i(a_i+b) bitwise. 4 bias adds -> 1. (exact)
//   3. Linear 18-fma -> 9 v_pk_fma_f32 + 1 combine add (two interleaved
//      9-chains; last-ulp summation-order change, same error class as the
//      quad-tree reduce).
// Everything else identical to R11: G=6 steps/barrier, 16-deep s_bits/s_p,
// 4+2 conv split, shfl quad-reduce, 2-group-deferred stores.
// Requires T % 6 == 0, T >= 18.

typedef float v2f __attribute__((ext_vector_type(2)));

__global__ __launch_bounds__(128, 4) void snn_step_kernel(
    const float* __restrict__ x,       // [B,1,15,15]
    const float* __restrict__ conv_w,  // [2,1,4,4]
    const float* __restrict__ conv_b,  // [2]
    const float* __restrict__ lin_w,   // [10,72]
    const float* __restrict__ lin_b,   // [10]
    float* __restrict__ out,           // spk_out[B,10] ++ mem_rec[T,B,10] ++ spk_rec[T,B,10]
    int T, int B)
{
    const int b   = blockIdx.x;
    const int tid = threadIdx.x;
    const int w   = tid & 63;
    const int wv  = tid >> 6;   // 0 = enc + 4conv, 1 = 2conv + lin + dec

    __shared__ float    s_linw[720];
    __shared__ float    s_linb[10];
    __shared__ float4   s_lut[4][32];   // [ky][5-bit row bits] -> 4 partial sums
    __shared__ unsigned s_bits[16][8];  // 16-deep packed spike rows (8 words used)
    __shared__ float    s_p[16][80];    // 16-deep pooled outputs (4 chunks x 20)

    // ---- cooperative staging (128 threads) ----
    for (int j = tid; j < 720; j += 128) s_linw[j] = lin_w[j];
    if (tid < 10) s_linb[tid] = lin_b[tid];
    {
        const int ky = tid >> 5, n = tid & 31;
        float s00 = 0.f, s01 = 0.f, s10 = 0.f, s11 = 0.f;
#pragma unroll
        for (int kx = 0; kx < 4; ++kx) {
            const float w0 = conv_w[ky * 4 + kx];        // ch0
            const float w1 = conv_w[16 + ky * 4 + kx];   // ch1
            if ((n >> kx) & 1)       { s00 += w0; s01 += w1; }  // dx = 0
            if ((n >> (kx + 1)) & 1) { s10 += w0; s11 += w1; }  // dx = 1
        }
        s_lut[ky][n] = make_float4(s00, s01, s10, s11);
    }
    __syncthreads();

    // ===== encoder state (wave0 only; wave1 lanes hold zeros), packed =====
    v2f ve01 = (v2f){0.f, 0.f}, ve23 = (v2f){0.f, 0.f};
    v2f cur01, cur23;
    {
        const int jrow = w >> 4, col = w & 15;
        float c[4];
#pragma unroll
        for (int k = 0; k < 4; ++k) {
            const int  row = 4 * k + jrow;
            const bool act = (col < 15) && (row < 15) && (wv == 0);
            c[k] = act ? __fmul_rn(x[(size_t)b * 225 + row * 15 + col], 10.0f) : 0.f;
        }
        cur01 = (v2f){c[0], c[1]};
        cur23 = (v2f){c[2], c[3]};
    }

    // ===== conv lane params (used by both waves) =====
    const bool convlane = (w < 36);
    const int  py = w / 6, px = w - 6 * py;
    const int  wordsel = py;                 // words py..py+2 hold rows 2py..2py+5
    const int  shx = 2 * px, shx16 = shx + 16;
    const int  off0 = (w < 18) ? w : (w + 2);
    const v2f  cb2 = (v2f){conv_b[0], conv_b[1]};

    // ===== lin/decoder lane params (wave1) =====
    const int lo = w >> 2, lq = w & 3;
    v2f lw2[9];
#pragma unroll
    for (int jj = 0; jj < 9; ++jj) {
        int i0 = lo * 72 + lq * 18 + 2 * jj;
        int i1 = i0 + 1;
        lw2[jj] = (v2f){s_linw[i0 < 720 ? i0 : 719],
                        s_linw[i1 < 720 ? i1 : 719]};   // clamp for lanes >= 40
    }
    const float lbias = s_linb[lo < 10 ? lo : 0];
    float v = 0.f, i_syn = 0.f, sc = 0.f;
    float svv[6], svs[6];
    const size_t BO = (size_t)B * 10;
    float* mp  = out + BO + (size_t)b * 10 + lo;
    float* spp = out + BO + (size_t)T * BO + (size_t)b * 10 + lo;

    // encoder step (packed update) + ballot bit-pack -> s_bits[slot]
    auto enc_pack = [&](int slot) {
        const v2f tenth = (v2f){0.1f, 0.1f};
        v2f vn01 = ve01 + (cur01 - ve01) * tenth;   // pk sub/mul/add: IEEE per half
        v2f vn23 = ve23 + (cur23 - ve23) * tenth;
        bool sp0 = (vn01.x > 1.0f);
        bool sp1 = (vn01.y > 1.0f);
        bool sp2 = (vn23.x > 1.0f);
        bool sp3 = (vn23.y > 1.0f);
        unsigned long long bal0 = __ballot(sp0);
        unsigned long long bal1 = __ballot(sp1);
        unsigned long long bal2 = __ballot(sp2);
        unsigned long long bal3 = __ballot(sp3);
        ve01 = (v2f){sp0 ? 0.f : vn01.x, sp1 ? 0.f : vn01.y};
        ve23 = (v2f){sp2 ? 0.f : vn23.x, sp3 ? 0.f : vn23.y};
        // masks are wave-uniform; lanes 0..7 pick their 32-bit word
        unsigned long long m01 = (w & 2) ? bal1 : bal0;
        unsigned long long m23 = (w & 2) ? bal3 : bal2;
        unsigned long long m   = (w & 4) ? m23 : m01;
        unsigned word = (unsigned)((w & 1) ? (m >> 32) : m);
        if (w < 8) s_bits[slot][w] = word;
    };

    // conv LUT compute from pre-read words -> s_p[slot]; bias after max (exact)
    auto conv_compute = [&](int slot, unsigned wb0, unsigned wb1, unsigned wb2) {
        const int i0 = (wb0 >> shx)   & 31;
        const int i1 = (wb0 >> shx16) & 31;
        const int i2 = (wb1 >> shx)   & 31;
        const int i3 = (wb1 >> shx16) & 31;
        const int i4 = (wb2 >> shx)   & 31;

        const float4 f0 = s_lut[0][i0];
        const float4 f1 = s_lut[1][i1];
        const float4 f2 = s_lut[2][i2];
        const float4 f3 = s_lut[3][i3];
        const float4 g0 = s_lut[0][i1];
        const float4 g1 = s_lut[1][i2];
        const float4 g2 = s_lut[2][i3];
        const float4 g3 = s_lut[3][i4];

        v2f a00 = (v2f){f0.x, f0.y};  a00 += (v2f){f1.x, f1.y};
        a00 += (v2f){f2.x, f2.y};     a00 += (v2f){f3.x, f3.y};
        v2f a01 = (v2f){f0.z, f0.w};  a01 += (v2f){f1.z, f1.w};
        a01 += (v2f){f2.z, f2.w};     a01 += (v2f){f3.z, f3.w};
        v2f a10 = (v2f){g0.x, g0.y};  a10 += (v2f){g1.x, g1.y};
        a10 += (v2f){g2.x, g2.y};     a10 += (v2f){g3.x, g3.y};
        v2f a11 = (v2f){g0.z, g0.w};  a11 += (v2f){g1.z, g1.w};
        a11 += (v2f){g2.z, g2.w};     a11 += (v2f){g3.z, g3.w};

        v2f mraw = __builtin_elementwise_max(
                       __builtin_elementwise_max(a00, a01),
                       __builtin_elementwise_max(a10, a11));
        v2f m2 = mraw + cb2;   // rn(x+b) monotone -> == max of (a_i + b) bitwise

        float* pbuf = s_p[slot];
        pbuf[off0]      = m2.x;   // p[w]
        pbuf[off0 + 40] = m2.y;   // p[36 + w]
    };

    // linear (packed fma) + decoder for step s; deferred store slot k
    auto lin_dec = [&](int s, int k) {
        const v2f* pp = (const v2f*)&s_p[s & 15][lq * 20];   // 8B-aligned
        v2f pv[9];
#pragma unroll
        for (int jj = 0; jj < 9; ++jj) pv[jj] = pp[jj];
        v2f pacc = (v2f){0.f, 0.f};
#pragma unroll
        for (int jj = 0; jj < 9; ++jj)
            pacc = __builtin_elementwise_fma(lw2[jj], pv[jj], pacc);
        float partial = __fadd_rn(pacc.x, pacc.y);

        // quad reduce (((p0+p1)+p2)+p3)+lbias on lq==0 lanes
        float p1 = __shfl_xor(partial, 1);
        float p2 = __shfl_xor(partial, 2);
        float p3 = __shfl_xor(partial, 3);
        float lin = __fadd_rn(
            __fadd_rn(__fadd_rn(__fadd_rn(partial, p1), p2), p3), lbias);

        float vd  = __fadd_rn(v, __fmul_rn(0.1f, __fsub_rn(i_syn, v)));
        float id  = __fsub_rn(i_syn, __fmul_rn(0.2f, i_syn));
        float spk = (vd > 1.0f) ? 1.0f : 0.0f;
        v = (vd > 1.0f) ? 0.0f : vd;
        sc += spk;
        svv[k] = v;
        svs[k] = spk;
        i_syn = __fadd_rn(id, lin);
    };

    auto issue_stores = [&]() {
        if (lq == 0 && lo < 10) {
#pragma unroll
            for (int k = 0; k < 6; ++k) {
                mp[(size_t)k * BO]  = svv[k];
                spp[(size_t)k * BO] = svs[k];
            }
        }
        mp  += 6 * BO;
        spp += 6 * BO;
    };

    // ---- prologue: enc(0) -> bits[0] ----
    if (wv == 0) enc_pack(0);

    const int NG = T / 6;   // T % 6 == 0

    for (int g = 0; g < NG; ++g) {
        const int base = 6 * g;
        if (wv == 0) {
#pragma unroll
            for (int k = 0; k < 4; ++k) {
                const int s = base + k;
                unsigned wb0 = 0, wb1 = 0, wb2 = 0;
                if (convlane) {
                    const unsigned* bb = &s_bits[s & 15][wordsel];
                    wb0 = bb[0]; wb1 = bb[1]; wb2 = bb[2];
                }
                enc_pack((s + 1) & 15);              // enc hides the bit reads
                if (convlane) conv_compute(s & 15, wb0, wb1, wb2);
            }
            enc_pack((base + 5) & 15);
            enc_pack((base + 6) & 15);
        } else {
            if (g >= 2) issue_stores();              // group g-2
            if (g >= 1) {
                const int pb = base - 6;
                // conv for steps pb+4, pb+5 (bits from group g-1, barrier-safe)
                if (convlane) {
                    const unsigned* ba = &s_bits[(pb + 4) & 15][wordsel];
                    unsigned a0 = ba[0], a1 = ba[1], a2 = ba[2];
                    const unsigned* bc = &s_bits[(pb + 5) & 15][wordsel];
                    unsigned c0 = bc[0], c1 = bc[1], c2 = bc[2];
                    conv_compute((pb + 4) & 15, a0, a1, a2);
                    conv_compute((pb + 5) & 15, c0, c1, c2);
                }
#pragma unroll
                for (int k = 0; k < 6; ++k)          // lin+dec group g-1
                    lin_dec(pb + k, k);
            }
        }
        __syncthreads();
    }

    // ---- epilogue (wave1): stores NG-2, conv+lin+dec NG-1, stores NG-1 ----
    if (wv == 1) {
        issue_stores();                              // group NG-2
        const int pb = 6 * (NG - 1);
        if (convlane) {
            const unsigned* ba = &s_bits[(pb + 4) & 15][wordsel];
            unsigned a0 = ba[0], a1 = ba[1], a2 = ba[2];
            const unsigned* bc = &s_bits[(pb + 5) & 15][wordsel];
            unsigned c0 = bc[0], c1 = bc[1], c2 = bc[2];
            conv_compute((pb + 4) & 15, a0, a1, a2);
            conv_compute((pb + 5) & 15, c0, c1, c2);
        }
#pragma unroll
        for (int k = 0; k < 6; ++k)
            lin_dec(pb + k, k);
        issue_stores();                              // group NG-1
        if (lq == 0 && lo < 10) out[(size_t)b * 10 + lo] = sc;
    }
}

extern "C" void kernel_launch(void* const* d_in, const int* in_sizes, int n_in,
                              void* d_out, int out_size, void* d_ws, size_t ws_size,
                              hipStream_t stream) {
    const float* x      = (const float*)d_in[0];
    const float* conv_w = (const float*)d_in[1];
    const float* conv_b = (const float*)d_in[2];
    const float* lin_w  = (const float*)d_in[3];
    const float* lin_b  = (const float*)d_in[4];
    float* out = (float*)d_out;

    const int B = in_sizes[0] / 225;             // x is [B,1,15,15]
    const int T = (out_size / (B * 10) - 1) / 2; // out = B*10 * (1 + 2T); T=300

    snn_step_kernel<<<B, 128, 0, stream>>>(x, conv_w, conv_b, lin_w, lin_b, out, T, B);
}